// Round 4
// baseline (3343.505 us; speedup 1.0000x reference)
//
#include <hip/hip_runtime.h>
#include <hip/hip_bf16.h>

// SAGEClassifier: h[50000,256] --conv1(LSTM-agg)--> h1[50000,128] --conv2--> h2[50000,128]
//   --segment_max(256 graphs)--> hg[256,128] --linear--> out[256,10]
//
// Round 4: pipeline the LSTM kernel (round-3 limit was barrier-drained gather latency
// + scalar LDS acc-init; no pipe >35% busy).
//  - gathers depend only on nidx -> prefetch iter ii+1's gather at top of iter ii,
//    double-buffered hinS, ds_write after compute, ONE barrier per (t,dc) iter.
//  - acc-init via identity-MFMA (B=I fragment): 8 ds_read_b128 + 8 MFMA per dc
//    instead of 128 scalar ds_read_u16 per step. Exact numerics (bf16*1.0 -> f32).
//  - gemm_nt still fp32 (isolate; MFMA-ize next round).

#define NNODES  50000
#define DEG     16
#define INDIM   256
#define HIDDIM  128
#define NCLS    10
#define NGRAPH  256

typedef __hip_bfloat16 bf16;
typedef short bf16x8 __attribute__((ext_vector_type(8)));
typedef float f32x4  __attribute__((ext_vector_type(4)));

__device__ __forceinline__ float sigf(float x) {
    x = fminf(fmaxf(x, -30.f), 30.f);
    return 1.0f / (1.0f + __expf(-x));
}
__device__ __forceinline__ float tanhfast(float x) {
    x = fminf(fmaxf(x, -15.f), 15.f);
    float e = __expf(2.0f * x);
    return (e - 1.0f) / (e + 1.0f);
}
__device__ __forceinline__ float b2f(unsigned short u) {
    return __uint_as_float(((unsigned)u) << 16);
}
__device__ __forceinline__ unsigned short f2b(float f) {  // RNE bf16
    unsigned u = __float_as_uint(f);
    return (unsigned short)((u + 0x7FFF + ((u >> 16) & 1)) >> 16);
}

__global__ void f2bf_k(const float* __restrict__ in, unsigned short* __restrict__ out, int n) {
    int i = blockIdx.x * 256 + threadIdx.x;
    if (i < n) out[i] = f2b(in[i]);
}

// ---------------- fp32 tiled GEMM (unchanged) ----------------
template<bool RELU, bool DUAL, bool BF16OUT>
__global__ __launch_bounds__(256) void gemm_nt(
    const float* __restrict__ A, const float* __restrict__ B,
    const float* __restrict__ A2, const float* __restrict__ B2,
    const float* __restrict__ bias0, const float* __restrict__ bias1,
    void* __restrict__ Cout, int M, int Ncol, int K, int K2)
{
    __shared__ float As[16][68];
    __shared__ float Bs[16][68];
    const int tid = threadIdx.x;
    const int m0 = blockIdx.y * 64;
    const int j0 = blockIdx.x * 64;
    const int tx = tid & 15;
    const int ty = tid >> 4;
    const int am = tid >> 2;
    const int ak = (tid & 3) * 4;
    float c[4][4] = {};

    const int npass = DUAL ? 2 : 1;
    for (int pass = 0; pass < npass; ++pass) {
        const float* Ap = (DUAL && pass) ? A2 : A;
        const float* Bp = (DUAL && pass) ? B2 : B;
        const int Kp = (DUAL && pass) ? K2 : K;
        for (int kk = 0; kk < Kp; kk += 16) {
            float4 av = make_float4(0.f, 0.f, 0.f, 0.f);
            float4 bv = make_float4(0.f, 0.f, 0.f, 0.f);
            if (m0 + am < M)    av = *(const float4*)&Ap[(size_t)(m0 + am) * Kp + kk + ak];
            if (j0 + am < Ncol) bv = *(const float4*)&Bp[(size_t)(j0 + am) * Kp + kk + ak];
            __syncthreads();
            As[ak + 0][am] = av.x; As[ak + 1][am] = av.y;
            As[ak + 2][am] = av.z; As[ak + 3][am] = av.w;
            Bs[ak + 0][am] = bv.x; Bs[ak + 1][am] = bv.y;
            Bs[ak + 2][am] = bv.z; Bs[ak + 3][am] = bv.w;
            __syncthreads();
            #pragma unroll
            for (int k = 0; k < 16; ++k) {
                float4 a = *(const float4*)&As[k][ty * 4];
                float4 b = *(const float4*)&Bs[k][tx * 4];
                c[0][0] = fmaf(a.x, b.x, c[0][0]); c[0][1] = fmaf(a.x, b.y, c[0][1]);
                c[0][2] = fmaf(a.x, b.z, c[0][2]); c[0][3] = fmaf(a.x, b.w, c[0][3]);
                c[1][0] = fmaf(a.y, b.x, c[1][0]); c[1][1] = fmaf(a.y, b.y, c[1][1]);
                c[1][2] = fmaf(a.y, b.z, c[1][2]); c[1][3] = fmaf(a.y, b.w, c[1][3]);
                c[2][0] = fmaf(a.z, b.x, c[2][0]); c[2][1] = fmaf(a.z, b.y, c[2][1]);
                c[2][2] = fmaf(a.z, b.z, c[2][2]); c[2][3] = fmaf(a.z, b.w, c[2][3]);
                c[3][0] = fmaf(a.w, b.x, c[3][0]); c[3][1] = fmaf(a.w, b.y, c[3][1]);
                c[3][2] = fmaf(a.w, b.z, c[3][2]); c[3][3] = fmaf(a.w, b.w, c[3][3]);
            }
        }
    }
    #pragma unroll
    for (int i = 0; i < 4; ++i) {
        int m = m0 + ty * 4 + i;
        if (m >= M) continue;
        #pragma unroll
        for (int jj = 0; jj < 4; ++jj) {
            int j = j0 + tx * 4 + jj;
            if (j >= Ncol) continue;
            float v = c[i][jj];
            if (bias0) v += bias0[j];
            if (bias1) v += bias1[j];
            if (RELU) v = fmaxf(v, 0.f);
            if (BF16OUT) ((bf16*)Cout)[(size_t)m * Ncol + j] = __float2bfloat16(v);
            else         ((float*)Cout)[(size_t)m * Ncol + j] = v;
        }
    }
}

// ---------------- pipelined MFMA fused LSTM ----------------
// Block: TNODE=32 nodes, 256 threads (4 waves). Wave w owns d-cols [w*16,w*16+16)
// of each 64-d chunk, all 4 gates -> i/f/g/o of one (node,d) share a lane+reg.
// C-fragment: node = m*16 + (lane>>4)*4 + reg, d = dc*64 + w*16 + (lane&15).
template<int D, int TNODE>
__global__ __launch_bounds__(256, 2) void lstm_mfma(
    const unsigned short* __restrict__ Hin,   // [Nn,4D] bf16 bits (bias folded)
    const unsigned short* __restrict__ Wb,    // [4D,D]  bf16 bits (W_hh row-major)
    const int* __restrict__ nidx,             // [Nn,DEG]
    float* __restrict__ hout,                 // [Nn,D]
    int Nn)
{
    constexpr int FD    = 4 * D;
    constexpr int KCH   = D / 32;      // K chunks of 32
    constexpr int DCH   = D / 64;      // d chunks of 64
    constexpr int MT    = TNODE / 16;  // MFMA m-tiles
    constexpr int LDA   = D + 8;       // hS row stride (16B-aligned rows)
    constexpr int LDH   = 264;         // hinS row stride (4 gates x 64 + 8 pad)
    constexpr int SITER = TNODE / 8;   // staging iters (32 thr x 16B = 512B per row)
    constexpr int NIT   = DEG * DCH;   // total pipeline iterations

    __shared__ unsigned short hS[2][TNODE * LDA];    // double-buffered h_state
    __shared__ unsigned short hinS[2][TNODE * LDH];  // double-buffered gathered Hin
    __shared__ int nidS[TNODE * DEG];

    const int tid  = threadIdx.x;
    const int wid  = tid >> 6;
    const int lane = tid & 63;
    const int lg   = lane >> 4;
    const int lr   = lane & 15;
    const int nb   = blockIdx.x * TNODE;

    for (int i = tid; i < TNODE * DEG; i += 256) {
        int node = nb + (i >> 4);
        nidS[i] = (node < Nn) ? nidx[node * DEG + (i & 15)] : 0;
    }

    // identity B-fragment: B[col=lr][k=lg*8+j] = (lg*8+j == lr) ? 1.0bf16 : 0
    bf16x8 bI;
    #pragma unroll
    for (int j = 0; j < 8; ++j)
        bI[j] = (short)((lg * 8 + j == lr) ? 0x3F80 : 0);

    float c[DCH][MT][4];
    #pragma unroll
    for (int dc = 0; dc < DCH; ++dc)
        #pragma unroll
        for (int m = 0; m < MT; ++m)
            #pragma unroll
            for (int r = 0; r < 4; ++r) c[dc][m][r] = 0.f;

    const int srow = tid >> 5;           // staging: node row per thread group
    const int scol = tid & 31;           // 32 threads x 16B = one 512B slice
    const int sg   = scol >> 3;          // gate
    const int sc8  = scol & 7;           // 8-col group

    __syncthreads();   // nidS ready

    // ---- prologue: stage iter 0 (t=0, dc=0) ----
    {
        uint4 stg[SITER];
        #pragma unroll
        for (int it = 0; it < SITER; ++it) {
            int nbr = nidS[(srow + it * 8) * DEG + 0];
            stg[it] = *(const uint4*)&Hin[(size_t)nbr * FD + sg * D + sc8 * 8];
        }
        #pragma unroll
        for (int it = 0; it < SITER; ++it)
            *(uint4*)&hinS[0][(srow + it * 8) * LDH + scol * 8] = stg[it];
    }
    __syncthreads();

    int cur = 0;    // hinS buffer holding current iter's data
    int hcur = 0;   // hS buffer holding current step's h_state

    #pragma unroll 1
    for (int ii = 0; ii < NIT; ++ii) {
        const int t  = ii / DCH;
        const int dc = ii % DCH;

        // ---- 1. prefetch next iter's gather (independent of all compute) ----
        uint4 stg[SITER];
        if (ii + 1 < NIT) {
            const int t2  = (ii + 1) / DCH;
            const int dc2 = (ii + 1) % DCH;
            #pragma unroll
            for (int it = 0; it < SITER; ++it) {
                int nbr = nidS[(srow + it * 8) * DEG + t2];
                stg[it] = *(const uint4*)&Hin[(size_t)nbr * FD + sg * D + dc2 * 64 + sc8 * 8];
            }
        }

        // ---- 2. acc init from hinS[cur] via identity MFMA ----
        f32x4 acc[4][MT];
        #pragma unroll
        for (int g = 0; g < 4; ++g)
            #pragma unroll
            for (int m = 0; m < MT; ++m) {
                #pragma unroll
                for (int r = 0; r < 4; ++r) acc[g][m][r] = 0.f;
                bf16x8 aI = *(const bf16x8*)&hinS[cur][(m * 16 + lr) * LDH + g * 64 + wid * 16 + (lg & 1) * 8];
                acc[g][m] = __builtin_amdgcn_mfma_f32_16x16x32_bf16(aI, bI, acc[g][m], 0, 0, 0);
            }

        // ---- 3. recurrent GEMM: acc += h_state @ W_hh^T (wave's col slice) ----
        if (t > 0) {
            #pragma unroll
            for (int kk = 0; kk < KCH; ++kk) {
                bf16x8 b[4];
                #pragma unroll
                for (int g = 0; g < 4; ++g)
                    b[g] = *(const bf16x8*)&Wb[(size_t)(g * D + dc * 64 + wid * 16 + lr) * D + kk * 32 + lg * 8];
                #pragma unroll
                for (int m = 0; m < MT; ++m) {
                    bf16x8 a = *(const bf16x8*)&hS[hcur][(m * 16 + lr) * LDA + kk * 32 + lg * 8];
                    #pragma unroll
                    for (int g = 0; g < 4; ++g)
                        acc[g][m] = __builtin_amdgcn_mfma_f32_16x16x32_bf16(a, b[g], acc[g][m], 0, 0, 0);
                }
            }
        }

        // ---- 4. LSTM nonlinearity; h_new -> hS[hcur^1] (or hout on last step) ----
        #pragma unroll
        for (int m = 0; m < MT; ++m)
            #pragma unroll
            for (int r = 0; r < 4; ++r) {
                float ig = sigf(acc[0][m][r]);
                float fg = sigf(acc[1][m][r]);
                float gg = tanhfast(acc[2][m][r]);
                float og = sigf(acc[3][m][r]);
                float cv = fg * c[dc][m][r] + ig * gg;
                c[dc][m][r] = cv;
                float hv = og * tanhfast(cv);
                if (t < DEG - 1) {
                    hS[hcur ^ 1][(m * 16 + lg * 4 + r) * LDA + dc * 64 + wid * 16 + lr] = f2b(hv);
                } else {
                    int node = nb + m * 16 + lg * 4 + r;
                    if (node < Nn)
                        hout[(size_t)node * D + dc * 64 + wid * 16 + lr] = hv;
                }
            }

        // ---- 5. publish next iter's hinS (vmcnt wait lands after long compute) ----
        if (ii + 1 < NIT) {
            #pragma unroll
            for (int it = 0; it < SITER; ++it)
                *(uint4*)&hinS[cur ^ 1][(srow + it * 8) * LDH + scol * 8] = stg[it];
        }
        __syncthreads();   // hinS[cur^1] + hS[hcur^1] writes visible; hS/hinS reads done

        cur ^= 1;
        if (dc == DCH - 1) hcur ^= 1;
    }
}

// ---------------- readout ----------------
__global__ void segmax_k(const float* __restrict__ h2, const int* __restrict__ gid,
                         float* __restrict__ hg, int Nn) {
    int g = blockIdx.x;
    int d = threadIdx.x;   // 128
    __shared__ int sb[2];
    if (d < 2) {
        int target = g + d;
        int lo = 0, hi = Nn;
        while (lo < hi) { int mid = (lo + hi) >> 1; if (gid[mid] < target) lo = mid + 1; else hi = mid; }
        sb[d] = lo;
    }
    __syncthreads();
    int lo = sb[0], hi = sb[1];
    float m = -INFINITY;
    for (int r = lo; r < hi; ++r) m = fmaxf(m, h2[(size_t)r * HIDDIM + d]);
    hg[g * HIDDIM + d] = m;
}

__global__ void cls_k(const float* __restrict__ hg, const float* __restrict__ W,
                      const float* __restrict__ b, float* __restrict__ out) {
    int idx = blockIdx.x * 256 + threadIdx.x;
    if (idx >= NGRAPH * NCLS) return;
    int g = idx / NCLS, cc = idx % NCLS;
    float s = b[cc];
    const float* hp = hg + g * HIDDIM;
    const float* wp = W + cc * HIDDIM;
    #pragma unroll 8
    for (int k = 0; k < HIDDIM; ++k) s = fmaf(hp[k], wp[k], s);
    out[idx] = s;
}

extern "C" void kernel_launch(void* const* d_in, const int* in_sizes, int n_in,
                              void* d_out, int out_size, void* d_ws, size_t ws_size,
                              hipStream_t stream)
{
    const float* h       = (const float*)d_in[0];
    const int*   nidx    = (const int*)d_in[1];
    const int*   gids    = (const int*)d_in[2];
    const float* W_ih1   = (const float*)d_in[3];
    const float* W_hh1   = (const float*)d_in[4];
    const float* b_ih1   = (const float*)d_in[5];
    const float* b_hh1   = (const float*)d_in[6];
    const float* W_self1 = (const float*)d_in[7];
    const float* W_neigh1= (const float*)d_in[8];
    const float* b1      = (const float*)d_in[9];
    const float* W_ih2   = (const float*)d_in[10];
    const float* W_hh2   = (const float*)d_in[11];
    const float* b_ih2   = (const float*)d_in[12];
    const float* b_hh2   = (const float*)d_in[13];
    const float* W_self2 = (const float*)d_in[14];
    const float* W_neigh2= (const float*)d_in[15];
    const float* b2      = (const float*)d_in[16];
    const float* W_cls   = (const float*)d_in[17];
    const float* b_cls   = (const float*)d_in[18];
    float* out = (float*)d_out;

    // ws layout (16B-aligned chunks)
    char* ws = (char*)d_ws;
    unsigned short* Hin    = (unsigned short*)(ws);            // 102,400,000
    float*          hneigh = (float*)(ws + 102400000);         //  51,200,000
    float*          h1     = (float*)(ws + 153600000);         //  25,600,000
    float*          h2     = (float*)(ws + 179200000);         //  25,600,000
    float*          hg     = (float*)(ws + 204800000);         //     131,072
    unsigned short* Wb1    = (unsigned short*)(ws + 204931072);//     524,288
    unsigned short* Wb2    = (unsigned short*)(ws + 205455360);//     131,072

    // W_hh -> bf16 (row-major kept: B-fragment source)
    f2bf_k<<<dim3((262144 + 255) / 256), 256, 0, stream>>>(W_hh1, Wb1, 262144);
    f2bf_k<<<dim3((65536 + 255) / 256), 256, 0, stream>>>(W_hh2, Wb2, 65536);

    const int MB = (NNODES + 63) / 64;
    const int NB32 = (NNODES + 31) / 32;   // 1563 LSTM blocks

    // ---- conv1 ----
    gemm_nt<false, false, true><<<dim3(1024 / 64, MB), 256, 0, stream>>>(
        h, W_ih1, nullptr, nullptr, b_ih1, b_hh1, Hin, NNODES, 1024, 256, 0);
    lstm_mfma<256, 32><<<dim3(NB32), 256, 0, stream>>>(Hin, Wb1, nidx, hneigh, NNODES);
    gemm_nt<true, true, false><<<dim3(HIDDIM / 64, MB), 256, 0, stream>>>(
        h, W_self1, hneigh, W_neigh1, b1, nullptr, h1, NNODES, HIDDIM, 256, 256);

    // ---- conv2 ----
    gemm_nt<false, false, true><<<dim3(512 / 64, MB), 256, 0, stream>>>(
        h1, W_ih2, nullptr, nullptr, b_ih2, b_hh2, Hin, NNODES, 512, 128, 0);
    lstm_mfma<128, 32><<<dim3(NB32), 256, 0, stream>>>(Hin, Wb2, nidx, hneigh, NNODES);
    gemm_nt<true, true, false><<<dim3(HIDDIM / 64, MB), 256, 0, stream>>>(
        h1, W_self2, hneigh, W_neigh2, b2, nullptr, h2, NNODES, HIDDIM, 128, 128);

    // ---- readout ----
    segmax_k<<<dim3(NGRAPH), 128, 0, stream>>>(h2, gids, hg, NNODES);
    cls_k<<<dim3((NGRAPH * NCLS + 255) / 256), 256, 0, stream>>>(hg, W_cls, b_cls, out);
}